// Round 1
// baseline (1010.736 us; speedup 1.0000x reference)
//
#include <hip/hip_runtime.h>
#include <math.h>
#include <stdint.h>

// HashEmbedder: 16-level multiresolution hash grid, trilinear interp.
// One thread per (point, level); level = tid & 15 so the float2 feature
// store is fully coalesced (wave writes 512B contiguous).

#define NLEVELS 16
#define HASH_MASK 0x7FFFFu
#define TABLE_ENTRIES 524288  // 2^19 entries of float2

struct ResTable { float r[NLEVELS]; };

__global__ __launch_bounds__(256) void hash_embed_kernel(
    const float* __restrict__ x,
    const float* __restrict__ emb,
    const float* __restrict__ bbox,
    float* __restrict__ out,
    float* __restrict__ mask,
    int n_points,
    ResTable rt)
{
    __shared__ float s_res[NLEVELS];
    if (threadIdx.x < NLEVELS) s_res[threadIdx.x] = rt.r[threadIdx.x];
    __syncthreads();

    int tid = blockIdx.x * 256 + threadIdx.x;
    int point = tid >> 4;
    int level = tid & 15;
    if (point >= n_points) return;

    float bmin0 = bbox[0], bmin1 = bbox[1], bmin2 = bbox[2];
    float bmax0 = bbox[3], bmax1 = bbox[4], bmax2 = bbox[5];

    const float* xp = x + (size_t)point * 3;
    float x0 = xp[0], x1 = xp[1], x2 = xp[2];

    // keep_mask = all((x >= box_min) & (x <= box_max))
    if (level == 0) {
        bool keep = (x0 >= bmin0) & (x0 <= bmax0) &
                    (x1 >= bmin1) & (x1 <= bmax1) &
                    (x2 >= bmin2) & (x2 <= bmax2);
        mask[point] = keep ? 1.0f : 0.0f;
    }

    // xc = clip(x, box_min, box_max)
    float xc0 = fminf(fmaxf(x0, bmin0), bmax0);
    float xc1 = fminf(fmaxf(x1, bmin1), bmax1);
    float xc2 = fminf(fmaxf(x2, bmin2), bmax2);

    float res = s_res[level];
    // grid = (box_max - box_min) / res   (fp32, true division like reference)
    float g0 = (bmax0 - bmin0) / res;
    float g1 = (bmax1 - bmin1) / res;
    float g2 = (bmax2 - bmin2) / res;

    // bl = floor((xc - box_min) / grid)
    float f0 = floorf((xc0 - bmin0) / g0);
    float f1 = floorf((xc1 - bmin1) / g1);
    float f2 = floorf((xc2 - bmin2) / g2);
    int b0 = (int)f0;
    int b1 = (int)f1;
    int b2 = (int)f2;

    // vmin = bl * grid + box_min ; w = (x - vmin) / grid   (original x!)
    float vmin0 = f0 * g0 + bmin0;
    float vmin1 = f1 * g1 + bmin1;
    float vmin2 = f2 * g2 + bmin2;
    float wx = (x0 - vmin0) / g0;
    float wy = (x1 - vmin1) / g1;
    float wz = (x2 - vmin2) / g2;

    // hash: (cx*1 ^ cy*2654435761 ^ cz*805459861) & (2^19-1)
    uint32_t hx0 = (uint32_t)b0;
    uint32_t hx1 = (uint32_t)(b0 + 1);
    uint32_t hy0 = (uint32_t)b1 * 2654435761u;
    uint32_t hy1 = (uint32_t)(b1 + 1) * 2654435761u;
    uint32_t hz0 = (uint32_t)b2 * 805459861u;
    uint32_t hz1 = (uint32_t)(b2 + 1) * 805459861u;

    const float2* tbl = (const float2*)emb + (size_t)level * TABLE_ENTRIES;

    // corner order (i,j,k), index = i*4 + j*2 + k
    float2 v0 = tbl[(hx0 ^ hy0 ^ hz0) & HASH_MASK];
    float2 v1 = tbl[(hx0 ^ hy0 ^ hz1) & HASH_MASK];
    float2 v2 = tbl[(hx0 ^ hy1 ^ hz0) & HASH_MASK];
    float2 v3 = tbl[(hx0 ^ hy1 ^ hz1) & HASH_MASK];
    float2 v4 = tbl[(hx1 ^ hy0 ^ hz0) & HASH_MASK];
    float2 v5 = tbl[(hx1 ^ hy0 ^ hz1) & HASH_MASK];
    float2 v6 = tbl[(hx1 ^ hy1 ^ hz0) & HASH_MASK];
    float2 v7 = tbl[(hx1 ^ hy1 ^ hz1) & HASH_MASK];

    float omx = 1.0f - wx, omy = 1.0f - wy, omz = 1.0f - wz;

    // c00 = v0*(1-wx) + v4*wx ; etc. (same association as reference)
    float c00_0 = v0.x * omx + v4.x * wx;
    float c00_1 = v0.y * omx + v4.y * wx;
    float c01_0 = v1.x * omx + v5.x * wx;
    float c01_1 = v1.y * omx + v5.y * wx;
    float c10_0 = v2.x * omx + v6.x * wx;
    float c10_1 = v2.y * omx + v6.y * wx;
    float c11_0 = v3.x * omx + v7.x * wx;
    float c11_1 = v3.y * omx + v7.y * wx;

    float c0_0 = c00_0 * omy + c10_0 * wy;
    float c0_1 = c00_1 * omy + c10_1 * wy;
    float c1_0 = c01_0 * omy + c11_0 * wy;
    float c1_1 = c01_1 * omy + c11_1 * wy;

    float2 o;
    o.x = c0_0 * omz + c1_0 * wz;
    o.y = c0_1 * omz + c1_1 * wz;

    *(float2*)(out + (size_t)point * 32 + level * 2) = o;
}

extern "C" void kernel_launch(void* const* d_in, const int* in_sizes, int n_in,
                              void* d_out, int out_size, void* d_ws, size_t ws_size,
                              hipStream_t stream) {
    const float* x    = (const float*)d_in[0];
    const float* emb  = (const float*)d_in[1];
    const float* bbox = (const float*)d_in[2];
    int n_points = in_sizes[0] / 3;

    float* out  = (float*)d_out;
    float* mask = out + (size_t)n_points * 32;

    // Resolutions computed host-side in double with glibc exp/log/pow —
    // same (correctly-rounded, glibc>=2.28) libm path the numpy reference
    // uses. Levels 3/6/9/12/15 land ulp-close to exact integers
    // (32/64/128/256/512); host double math must match numpy's floor.
    ResTable rt;
    double b = exp((log(512.0) - log(16.0)) / 15.0);
    for (int l = 0; l < NLEVELS; ++l)
        rt.r[l] = (float)floor(16.0 * pow(b, (double)l));

    long long total = (long long)n_points * NLEVELS;
    int blocks = (int)((total + 255) / 256);
    hipLaunchKernelGGL(hash_embed_kernel, dim3(blocks), dim3(256), 0, stream,
                       x, emb, bbox, out, mask, n_points, rt);
}

// Round 2
// 607.774 us; speedup vs baseline: 1.6630x; 1.6630x over previous
//
#include <hip/hip_runtime.h>
#include <math.h>
#include <stdint.h>

// HashEmbedder, round 2: XCD-affine level partitioning.
// Each level table is 4 MB == one XCD's L2. Two gather phases (levels 0-7,
// 8-15); within a phase level = blockIdx.x % 8 rides the round-robin
// block->XCD dispatch so each XCD's gather working set is ONE table ->
// L2-resident. Results staged level-major in d_ws (coalesced), third kernel
// assembles point-major output + mask.

#define NLEVELS 16
#define HASH_MASK 0x7FFFFu
#define TABLE_ENTRIES 524288  // 2^19 entries of float2 per level

struct ResTable { float r[NLEVELS]; };

__device__ __forceinline__ float2 gather_one_level(
    const float* __restrict__ x, const float2* __restrict__ tbl,
    float bmin0, float bmin1, float bmin2,
    float bmax0, float bmax1, float bmax2,
    float res, int point)
{
    const float* xp = x + (size_t)point * 3;
    float x0 = xp[0], x1 = xp[1], x2 = xp[2];

    float xc0 = fminf(fmaxf(x0, bmin0), bmax0);
    float xc1 = fminf(fmaxf(x1, bmin1), bmax1);
    float xc2 = fminf(fmaxf(x2, bmin2), bmax2);

    float g0 = (bmax0 - bmin0) / res;
    float g1 = (bmax1 - bmin1) / res;
    float g2 = (bmax2 - bmin2) / res;

    float f0 = floorf((xc0 - bmin0) / g0);
    float f1 = floorf((xc1 - bmin1) / g1);
    float f2 = floorf((xc2 - bmin2) / g2);
    int b0 = (int)f0, b1 = (int)f1, b2 = (int)f2;

    float vmin0 = f0 * g0 + bmin0;
    float vmin1 = f1 * g1 + bmin1;
    float vmin2 = f2 * g2 + bmin2;
    float wx = (x0 - vmin0) / g0;
    float wy = (x1 - vmin1) / g1;
    float wz = (x2 - vmin2) / g2;

    uint32_t hx0 = (uint32_t)b0;
    uint32_t hx1 = (uint32_t)(b0 + 1);
    uint32_t hy0 = (uint32_t)b1 * 2654435761u;
    uint32_t hy1 = (uint32_t)(b1 + 1) * 2654435761u;
    uint32_t hz0 = (uint32_t)b2 * 805459861u;
    uint32_t hz1 = (uint32_t)(b2 + 1) * 805459861u;

    float2 v0 = tbl[(hx0 ^ hy0 ^ hz0) & HASH_MASK];
    float2 v1 = tbl[(hx0 ^ hy0 ^ hz1) & HASH_MASK];
    float2 v2 = tbl[(hx0 ^ hy1 ^ hz0) & HASH_MASK];
    float2 v3 = tbl[(hx0 ^ hy1 ^ hz1) & HASH_MASK];
    float2 v4 = tbl[(hx1 ^ hy0 ^ hz0) & HASH_MASK];
    float2 v5 = tbl[(hx1 ^ hy0 ^ hz1) & HASH_MASK];
    float2 v6 = tbl[(hx1 ^ hy1 ^ hz0) & HASH_MASK];
    float2 v7 = tbl[(hx1 ^ hy1 ^ hz1) & HASH_MASK];

    float omx = 1.0f - wx, omy = 1.0f - wy, omz = 1.0f - wz;

    float c00_0 = v0.x * omx + v4.x * wx;
    float c00_1 = v0.y * omx + v4.y * wx;
    float c01_0 = v1.x * omx + v5.x * wx;
    float c01_1 = v1.y * omx + v5.y * wx;
    float c10_0 = v2.x * omx + v6.x * wx;
    float c10_1 = v2.y * omx + v6.y * wx;
    float c11_0 = v3.x * omx + v7.x * wx;
    float c11_1 = v3.y * omx + v7.y * wx;

    float c0_0 = c00_0 * omy + c10_0 * wy;
    float c0_1 = c00_1 * omy + c10_1 * wy;
    float c1_0 = c01_0 * omy + c11_0 * wy;
    float c1_1 = c01_1 * omy + c11_1 * wy;

    float2 o;
    o.x = c0_0 * omz + c1_0 * wz;
    o.y = c0_1 * omz + c1_1 * wz;
    return o;
}

// One level per block: level = blockIdx.x % 8 + level_base (XCD affinity via
// round-robin dispatch), 256 points per block. Stores level-major: coalesced.
__global__ __launch_bounds__(256) void gather_level_kernel(
    const float* __restrict__ x,
    const float* __restrict__ emb,
    const float* __restrict__ bbox,
    float2* __restrict__ tmp,   // [NLEVELS][n_points]
    int n_points, int level_base, ResTable rt)
{
    int level = (blockIdx.x & 7) + level_base;
    int point = (blockIdx.x >> 3) * 256 + threadIdx.x;
    if (point >= n_points) return;

    float bmin0 = bbox[0], bmin1 = bbox[1], bmin2 = bbox[2];
    float bmax0 = bbox[3], bmax1 = bbox[4], bmax2 = bbox[5];

    const float2* tbl = (const float2*)emb + (size_t)level * TABLE_ENTRIES;
    float2 o = gather_one_level(x, tbl, bmin0, bmin1, bmin2,
                                bmax0, bmax1, bmax2, rt.r[level], point);
    tmp[(size_t)level * n_points + point] = o;
}

// Assemble point-major output + mask from level-major staging.
__global__ __launch_bounds__(256) void assemble_kernel(
    const float* __restrict__ x,
    const float2* __restrict__ tmp,
    const float* __restrict__ bbox,
    float* __restrict__ out,
    float* __restrict__ mask,
    int n_points)
{
    int p = blockIdx.x * 256 + threadIdx.x;
    if (p >= n_points) return;

    float4 o[8];
    float2* op = (float2*)o;
#pragma unroll
    for (int l = 0; l < NLEVELS; ++l)
        op[l] = tmp[(size_t)l * n_points + p];

    float4* dst = (float4*)(out + (size_t)p * 32);
#pragma unroll
    for (int j = 0; j < 8; ++j) dst[j] = o[j];

    float bmin0 = bbox[0], bmin1 = bbox[1], bmin2 = bbox[2];
    float bmax0 = bbox[3], bmax1 = bbox[4], bmax2 = bbox[5];
    const float* xp = x + (size_t)p * 3;
    float x0 = xp[0], x1 = xp[1], x2 = xp[2];
    bool keep = (x0 >= bmin0) & (x0 <= bmax0) &
                (x1 >= bmin1) & (x1 <= bmax1) &
                (x2 >= bmin2) & (x2 <= bmax2);
    mask[p] = keep ? 1.0f : 0.0f;
}

// Fallback (round-1 kernel): direct point-major writes, no workspace needed.
__global__ __launch_bounds__(256) void hash_embed_direct_kernel(
    const float* __restrict__ x,
    const float* __restrict__ emb,
    const float* __restrict__ bbox,
    float* __restrict__ out,
    float* __restrict__ mask,
    int n_points, ResTable rt)
{
    int tid = blockIdx.x * 256 + threadIdx.x;
    int point = tid >> 4;
    int level = tid & 15;
    if (point >= n_points) return;

    float bmin0 = bbox[0], bmin1 = bbox[1], bmin2 = bbox[2];
    float bmax0 = bbox[3], bmax1 = bbox[4], bmax2 = bbox[5];

    if (level == 0) {
        const float* xp = x + (size_t)point * 3;
        float x0 = xp[0], x1 = xp[1], x2 = xp[2];
        bool keep = (x0 >= bmin0) & (x0 <= bmax0) &
                    (x1 >= bmin1) & (x1 <= bmax1) &
                    (x2 >= bmin2) & (x2 <= bmax2);
        mask[point] = keep ? 1.0f : 0.0f;
    }

    const float2* tbl = (const float2*)emb + (size_t)level * TABLE_ENTRIES;
    float2 o = gather_one_level(x, tbl, bmin0, bmin1, bmin2,
                                bmax0, bmax1, bmax2, rt.r[level], point);
    *(float2*)(out + (size_t)point * 32 + level * 2) = o;
}

extern "C" void kernel_launch(void* const* d_in, const int* in_sizes, int n_in,
                              void* d_out, int out_size, void* d_ws, size_t ws_size,
                              hipStream_t stream) {
    const float* x    = (const float*)d_in[0];
    const float* emb  = (const float*)d_in[1];
    const float* bbox = (const float*)d_in[2];
    int n_points = in_sizes[0] / 3;

    float* out  = (float*)d_out;
    float* mask = out + (size_t)n_points * 32;

    // Host-side double libm matches numpy's resolution floor (levels
    // 3/6/9/12/15 are ulp-close to exact powers of two).
    ResTable rt;
    double b = exp((log(512.0) - log(16.0)) / 15.0);
    for (int l = 0; l < NLEVELS; ++l)
        rt.r[l] = (float)floor(16.0 * pow(b, (double)l));

    size_t tmp_bytes = (size_t)n_points * NLEVELS * sizeof(float2);
    if (ws_size >= tmp_bytes) {
        float2* tmp = (float2*)d_ws;
        int chunks = (n_points + 255) / 256;
        dim3 grid(chunks * 8);
        // Phase A: levels 0-7, one level per XCD slot -> L2-resident table.
        hipLaunchKernelGGL(gather_level_kernel, grid, dim3(256), 0, stream,
                           x, emb, bbox, tmp, n_points, 0, rt);
        // Phase B: levels 8-15.
        hipLaunchKernelGGL(gather_level_kernel, grid, dim3(256), 0, stream,
                           x, emb, bbox, tmp, n_points, 8, rt);
        hipLaunchKernelGGL(assemble_kernel, dim3(chunks), dim3(256), 0, stream,
                           x, tmp, bbox, out, mask, n_points);
    } else {
        long long total = (long long)n_points * NLEVELS;
        int blocks = (int)((total + 255) / 256);
        hipLaunchKernelGGL(hash_embed_direct_kernel, dim3(blocks), dim3(256), 0,
                           stream, x, emb, bbox, out, mask, n_points, rt);
    }
}